// Round 1
// baseline (226.106 us; speedup 1.0000x reference)
//
#include <hip/hip_runtime.h>
#include <hip/hip_bf16.h>

typedef __attribute__((ext_vector_type(8))) short  short8;
typedef __attribute__((ext_vector_type(4))) short  short4v;
typedef __attribute__((ext_vector_type(4))) float  float4v;

// QK^T: D = A(16x32) * B(32x16), both frags read row-major [pos][d] (m97 pattern)
#define MFMA_QK(A,B,C) __builtin_amdgcn_mfma_f32_16x16x32_bf16(A,B,C,0,0,0)
// PV: K=16 variant -- its B-frag layout (n=lane&15, k=quad*4+jj) exactly matches
// the C/D layout of the QK output (col=lane&15, row=quad*4+reg): zero-shuffle P feed.
#define MFMA_PV(A,B,C) __builtin_amdgcn_mfma_f32_16x16x16bf16_1k(A,B,C,0,0,0)

static __device__ __forceinline__ short f2bf(float x) {
  unsigned u = __float_as_uint(x);
  u += 0x7fffu + ((u >> 16) & 1u);   // RNE; inputs are finite
  return (short)(u >> 16);
}

// sin/cos of (2*pi*rev) with explicit period reduction (v_sin takes revolutions)
static __device__ __forceinline__ void rope_sc(float rev, float& sn, float& cs) {
  float fr = rev - floorf(rev);
  sn = __builtin_amdgcn_sinf(fr);
  cs = __builtin_amdgcn_cosf(fr);
}

// 10000^(-idx/32) / (2*pi): RoPE inv-freq expressed in revolutions
static __device__ __forceinline__ float invfreq_rev(int idx) {
  // log2(10000)/32 = 0.4152410118609203
  return exp2f(-0.41524101186092034f * (float)idx) * 0.15915494309189535f;
}

#define N_ 4096
#define D_ 64
#define W_ 128

__global__ __launch_bounds__(256, 2)
void la_fused(const float* __restrict__ qg, const float* __restrict__ kg,
              const float* __restrict__ vg, float* __restrict__ outg)
{
  // K rows padded 64->72 bf16 (144B = 9*16B: keeps 16B-aligned b128 frag reads, breaks bank stride)
  __shared__ __attribute__((aligned(16))) short Kl[256][72];
  // V transposed, rows padded 256->264 (528B)
  __shared__ __attribute__((aligned(16))) short Vl[64][264];

  const int blk  = blockIdx.x;
  const int w    = blk & 31;     // window index 0..31
  const int bh   = blk >> 5;     // head 0..63
  const int base = bh * (N_ * D_);
  const int tid  = threadIdx.x;

  // ---------------- stage K (RoPE'd, bf16) and V^T (bf16) ----------------
  {
    const float* kb = kg + base;
    const float* vb = vg + base;
#pragma unroll
    for (int it = 0; it < 8; ++it) {
      int tau = it * 256 + tid;
      int j   = tau >> 3;          // key row in window: 0..255
      int d0  = (tau & 7) << 2;    // 0,4,...,28
      int g   = w * W_ - W_ + j;   // absolute position (negative => pad)
      float klo[4], khi[4], vlo[4], vhi[4];
      if (g < 0) {                 // look_around pad AFTER rope: exact -1.0
#pragma unroll
        for (int dd = 0; dd < 4; ++dd) { klo[dd]=khi[dd]=vlo[dd]=vhi[dd] = -1.0f; }
      } else {
        float4v a   = *(const float4v*)(kb + g * D_ + d0);
        float4v b   = *(const float4v*)(kb + g * D_ + d0 + 32);
        float4v va  = *(const float4v*)(vb + g * D_ + d0);
        float4v vb2 = *(const float4v*)(vb + g * D_ + d0 + 32);
        const float t = (float)g;
#pragma unroll
        for (int dd = 0; dd < 4; ++dd) {
          float sn, cs; rope_sc(t * invfreq_rev(d0 + dd), sn, cs);
          klo[dd] = a[dd] * cs - b[dd] * sn;   // d < 32: rot = -x[d+32]
          khi[dd] = b[dd] * cs + a[dd] * sn;   // d >= 32: rot = +x[d-32]
          vlo[dd] = va[dd]; vhi[dd] = vb2[dd];
        }
      }
      short4v k0 = { f2bf(klo[0]), f2bf(klo[1]), f2bf(klo[2]), f2bf(klo[3]) };
      short4v k1 = { f2bf(khi[0]), f2bf(khi[1]), f2bf(khi[2]), f2bf(khi[3]) };
      *(short4v*)&Kl[j][d0]      = k0;
      *(short4v*)&Kl[j][d0 + 32] = k1;
#pragma unroll
      for (int dd = 0; dd < 4; ++dd) {
        Vl[d0 + dd][j]      = f2bf(vlo[dd]);
        Vl[d0 + 32 + dd][j] = f2bf(vhi[dd]);
      }
    }
  }
  __syncthreads();

  const int lane = tid & 63;
  const int wv   = tid >> 6;      // wave 0..3: owns query rows wv*32..wv*32+31
  const int il   = lane & 15;
  const int qd   = lane >> 4;     // quad 0..3

  // ---------------- Q fragments (RoPE'd), loaded direct from global ------
  // B-frag of QK mfma: n = lane&15 = query row, k = quad*8+jj = d
  short8 qf[2][2];
#pragma unroll
  for (int ii = 0; ii < 2; ++ii) {
    const int rw = wv * 32 + ii * 16 + il;     // query row in window
    const int n  = w * W_ + rw;                // absolute position
    const float* qr = qg + base + n * D_ + qd * 8;
    float4v x0 = *(const float4v*)(qr);
    float4v x1 = *(const float4v*)(qr + 4);
    float4v y0 = *(const float4v*)(qr + 32);
    float4v y1 = *(const float4v*)(qr + 36);
    float lo[8], hi[8];
    const float t = (float)n;
#pragma unroll
    for (int jj = 0; jj < 8; ++jj) {
      const int d = qd * 8 + jj;               // always < 32
      float xx = (jj < 4) ? x0[jj & 3] : x1[jj & 3];
      float yy = (jj < 4) ? y0[jj & 3] : y1[jj & 3];
      float sn, cs; rope_sc(t * invfreq_rev(d), sn, cs);
      lo[jj] = xx * cs - yy * sn;
      hi[jj] = yy * cs + xx * sn;
    }
    qf[ii][0] = short8{ f2bf(lo[0]),f2bf(lo[1]),f2bf(lo[2]),f2bf(lo[3]),
                        f2bf(lo[4]),f2bf(lo[5]),f2bf(lo[6]),f2bf(lo[7]) };
    qf[ii][1] = short8{ f2bf(hi[0]),f2bf(hi[1]),f2bf(hi[2]),f2bf(hi[3]),
                        f2bf(hi[4]),f2bf(hi[5]),f2bf(hi[6]),f2bf(hi[7]) };
  }

  // ---------------- S^T = K * Q^T (256 keys x 32 queries per wave) -------
  float4v S[2][16];
#pragma unroll
  for (int ii = 0; ii < 2; ++ii)
#pragma unroll
    for (int t = 0; t < 16; ++t) { float4v z = {0.f,0.f,0.f,0.f}; S[ii][t] = z; }

#pragma unroll
  for (int t = 0; t < 16; ++t) {
    // A-frag: m = lane&15 = key row (tile t), k = quad*8+jj = d
    short8 a0 = *(const short8*)&Kl[t * 16 + il][qd * 8];
    short8 a1 = *(const short8*)&Kl[t * 16 + il][32 + qd * 8];
#pragma unroll
    for (int ii = 0; ii < 2; ++ii) {
      S[ii][t] = MFMA_QK(a0, qf[ii][0], S[ii][t]);
      S[ii][t] = MFMA_QK(a1, qf[ii][1], S[ii][t]);
    }
  }

  // ---------------- softmax over keys (rows of S^T), per query column ----
  // C layout: col = lane&15 = query, row = quad*4+reg = key j (tile t)
  short4v P[2][16];
  float   invsum[2];
#pragma unroll
  for (int ii = 0; ii < 2; ++ii) {
    const int rw = wv * 32 + ii * 16 + il;
    float mx = -3.0e38f;
#pragma unroll
    for (int t = 0; t < 16; ++t) {
#pragma unroll
      for (int r = 0; r < 4; ++r) {
        const int j = t * 16 + qd * 4 + r;
        float s = S[ii][t][r] * 0.125f;        // scale = D^-0.5
        if (j > rw + 128) s = -3.0e38f;        // causal mask (pad keys never masked)
        S[ii][t][r] = s;
        mx = fmaxf(mx, s);
      }
    }
    mx = fmaxf(mx, __shfl_xor(mx, 16));
    mx = fmaxf(mx, __shfl_xor(mx, 32));
    float sum = 0.0f;
#pragma unroll
    for (int t = 0; t < 16; ++t) {
#pragma unroll
      for (int r = 0; r < 4; ++r) {
        float p = __expf(S[ii][t][r] - mx);
        S[ii][t][r] = p;
        sum += p;
      }
    }
    sum += __shfl_xor(sum, 16);
    sum += __shfl_xor(sum, 32);
    invsum[ii] = 1.0f / sum;                   // folded into O epilogue
#pragma unroll
    for (int t = 0; t < 16; ++t) {
      P[ii][t] = short4v{ f2bf(S[ii][t][0]), f2bf(S[ii][t][1]),
                          f2bf(S[ii][t][2]), f2bf(S[ii][t][3]) };
    }
  }

  // ---------------- O^T = V^T * P^T ---------------------------------------
  float4v O[2][4];
#pragma unroll
  for (int ii = 0; ii < 2; ++ii)
#pragma unroll
    for (int dt = 0; dt < 4; ++dt) { float4v z = {0.f,0.f,0.f,0.f}; O[ii][dt] = z; }

#pragma unroll
  for (int c = 0; c < 16; ++c) {
    short4v af[4];
#pragma unroll
    for (int dt = 0; dt < 4; ++dt)   // A-frag: m=lane&15=d row of V^T, k=quad*4+jj=j
      af[dt] = *(const short4v*)&Vl[dt * 16 + il][c * 16 + qd * 4];
#pragma unroll
    for (int dt = 0; dt < 4; ++dt) {
      O[0][dt] = MFMA_PV(af[dt], P[0][c], O[0][dt]);
      O[1][dt] = MFMA_PV(af[dt], P[1][c], O[1][dt]);
    }
  }

  // ---------------- epilogue: normalize + store ---------------------------
  // O^T C layout: col = lane&15 = query (matches invsum lane ownership),
  // row = quad*4+reg = d  -> each lane stores float4 at d = dt*16 + quad*4
#pragma unroll
  for (int ii = 0; ii < 2; ++ii) {
    const int n = w * W_ + wv * 32 + ii * 16 + il;
    float* op = outg + base + n * D_;
    const float inv = invsum[ii];
#pragma unroll
    for (int dt = 0; dt < 4; ++dt) {
      float4v o = O[ii][dt];
      o[0] *= inv; o[1] *= inv; o[2] *= inv; o[3] *= inv;
      *(float4v*)(op + dt * 16 + qd * 4) = o;
    }
  }
}

extern "C" void kernel_launch(void* const* d_in, const int* in_sizes, int n_in,
                              void* d_out, int out_size, void* d_ws, size_t ws_size,
                              hipStream_t stream)
{
  const float* q = (const float*)d_in[0];
  const float* k = (const float*)d_in[1];
  const float* v = (const float*)d_in[2];
  float* out = (float*)d_out;
  la_fused<<<dim3(64 * 32), dim3(256), 0, stream>>>(q, k, v, out);
}